// Round 1
// baseline (449.351 us; speedup 1.0000x reference)
//
#include <hip/hip_runtime.h>
#include <hip/hip_bf16.h>

#define NHID 512
#define PROJ 64
#define NC 4096
#define NEV 8192
#define NG 64
#define NC_CHUNK 32
#define CHUNKS_PER_G 4   // caps Nc per graph at 128 (mean 64, 8 sigma headroom)
#define NE_CAP 256       // caps Ne per graph at 256 (mean 128, 11 sigma headroom)

typedef __hip_bfloat16 bf16;

// ---------------- k_pre: gather graph ids ----------------
__global__ void k_pre(const int* __restrict__ batch, const int* __restrict__ cidx,
                      const int* __restrict__ eidx, int* __restrict__ cb,
                      int* __restrict__ eb) {
  int i = blockIdx.x * 256 + threadIdx.x;
  if (i < NC) cb[i] = batch[cidx[i]];
  int j = i - NC;
  if (j >= 0 && j < NEV) eb[j] = batch[eidx[j]];
}

// ---------------- k_compact: stable per-graph compaction ----------------
__device__ void compact_one(const int* __restrict__ arr, int n, int g,
                            int* __restrict__ off_out, int* __restrict__ cnt_out,
                            int* __restrict__ list) {
  int t = threadIdx.x;
  int lane = t & 63, w = t >> 6;
  __shared__ int wsum[4];
  __shared__ int sless[4];
  int less = 0;
  for (int i = t; i < n; i += 256) less += (arr[i] < g) ? 1 : 0;
#pragma unroll
  for (int off = 32; off; off >>= 1) less += __shfl_xor(less, off);
  if (lane == 0) sless[w] = less;
  __syncthreads();
  int base = sless[0] + sless[1] + sless[2] + sless[3];
  if (t == 0) off_out[g] = base;
  int wbase = base;
  for (int chunk = 0; chunk < n; chunk += 256) {
    int i = chunk + t;
    bool f = (i < n) && (arr[i] == g);
    unsigned long long m = __ballot(f);
    if (lane == 0) wsum[w] = __popcll(m);
    __syncthreads();
    int prefix = 0;
    for (int k = 0; k < w; k++) prefix += wsum[k];
    int total = wsum[0] + wsum[1] + wsum[2] + wsum[3];
    if (f) list[wbase + prefix + __popcll(m & ((1ull << (unsigned)lane) - 1ull))] = i;
    wbase += total;
    __syncthreads();
  }
  if (t == 0) cnt_out[g] = wbase - base;
  __syncthreads();
}

__global__ __launch_bounds__(256) void k_compact(
    const int* __restrict__ cb, const int* __restrict__ eb,
    int* __restrict__ c_off, int* __restrict__ c_cnt, int* __restrict__ c_list,
    int* __restrict__ e_off, int* __restrict__ e_cnt, int* __restrict__ e_list) {
  int g = blockIdx.x;
  compact_one(cb, NC, g, c_off, c_cnt, c_list);
  compact_one(eb, NEV, g, e_off, e_cnt, e_list);
}

// ---------------- k_proj: weight_c / weight_e projections ----------------
// block = 64 threads, 8 rows per block (W reuse x8 from registers per wave)
__global__ __launch_bounds__(64) void k_proj(
    const float* __restrict__ x, const int* __restrict__ cidx,
    const int* __restrict__ eidx, const float* __restrict__ Wc,
    const float* __restrict__ bc, const float* __restrict__ We,
    const float* __restrict__ be, float* __restrict__ wcp, float* __restrict__ wep) {
  __shared__ float rows[8][NHID];
  int t = threadIdx.x;
  const float* W; const float* b; const int* idx; float* out; int base;
  if (blockIdx.x < NC / 8) {
    W = Wc; b = bc; idx = cidx; out = wcp; base = blockIdx.x * 8;
  } else {
    W = We; b = be; idx = eidx; out = wep; base = (blockIdx.x - NC / 8) * 8;
  }
  for (int r = 0; r < 8; r++) {
    const float4* src = (const float4*)(x + (size_t)idx[base + r] * NHID);
    float4* dst = (float4*)rows[r];
    dst[t] = src[t];
    dst[t + 64] = src[t + 64];
  }
  __syncthreads();
  float acc[8];
#pragma unroll
  for (int r = 0; r < 8; r++) acc[r] = b[t];
#pragma unroll 4
  for (int k = 0; k < NHID; k++) {
    float wv = W[k * PROJ + t];
#pragma unroll
    for (int r = 0; r < 8; r++) acc[r] += rows[r][k] * wv;
  }
  for (int r = 0; r < 8; r++) out[(size_t)(base + r) * PROJ + t] = acc[r];
}

// ---------------- k_attn: block-diagonal attention + fused pooled sums ----------------
__global__ __launch_bounds__(512) void k_attn(
    const float* __restrict__ x, const int* __restrict__ cidx,
    const int* __restrict__ eidx, const float* __restrict__ wcp,
    const float* __restrict__ wep, const int* __restrict__ c_off,
    const int* __restrict__ c_cnt, const int* __restrict__ c_list,
    const int* __restrict__ e_off, const int* __restrict__ e_cnt,
    const int* __restrict__ e_list, float* __restrict__ gs) {
  int g = blockIdx.x / CHUNKS_PER_G;
  int chunk = blockIdx.x % CHUNKS_PER_G;
  int t = threadIdx.x, lane = t & 63, w = t >> 6;
  int ne = min(e_cnt[g], NE_CAP);
  int eoff = e_off[g];
  int ccnt = c_cnt[g];
  int cbase = chunk * NC_CHUNK;
  int nloc = min(NC_CHUNK, ccnt - cbase);
  int coff = c_off[g] + cbase;

  __shared__ bf16 weT[PROJ][NE_CAP];        // transposed: lane-consecutive reads
  __shared__ bf16 wc_s[NC_CHUNK][PROJ + 2]; // broadcast reads
  __shared__ int ev_id[NE_CAP];

  for (int e = t; e < NE_CAP; e += 512) {
    if (e < ne) {
      int ep = e_list[eoff + e];
      ev_id[e] = eidx[ep];
      const float* wrow = wep + (size_t)ep * PROJ;
      for (int k = 0; k < PROJ; k++) weT[k][e] = __float2bfloat16(wrow[k]);
    } else {
      ev_id[e] = 0;
      for (int k = 0; k < PROJ; k++) weT[k][e] = __float2bfloat16(0.f);
    }
  }
  for (int c = t; c < NC_CHUNK; c += 512) {
    if (c < nloc) {
      int cp = c_list[coff + c];
      const float* crow = wcp + (size_t)cp * PROJ;
      for (int k = 0; k < PROJ; k++) wc_s[c][k] = __float2bfloat16(crow[k]);
    }
  }
  __syncthreads();
  if (nloc <= 0 || ne <= 0) return;

  float s_cl[8], s_cn[8], s_pr[8];
#pragma unroll
  for (int j = 0; j < 8; j++) { s_cl[j] = 0.f; s_cn[j] = 0.f; s_pr[j] = 0.f; }

  for (int l = w; l < nloc; l += 8) {
    // ---- scores: wc[l] . we[e] for e = lane + 64*jj
    float sc0 = 0.f, sc1 = 0.f, sc2 = 0.f, sc3 = 0.f;
#pragma unroll
    for (int k = 0; k < PROJ; k++) {
      float wcv = __bfloat162float(wc_s[l][k]);
      sc0 += wcv * __bfloat162float(weT[k][lane]);
      sc1 += wcv * __bfloat162float(weT[k][lane + 64]);
      sc2 += wcv * __bfloat162float(weT[k][lane + 128]);
      sc3 += wcv * __bfloat162float(weT[k][lane + 192]);
    }
    if (lane >= ne) sc0 = -1e30f;
    if (lane + 64 >= ne) sc1 = -1e30f;
    if (lane + 128 >= ne) sc2 = -1e30f;
    if (lane + 192 >= ne) sc3 = -1e30f;
    // ---- softmax over evidence of this graph (wave-wide)
    float mval = fmaxf(fmaxf(sc0, sc1), fmaxf(sc2, sc3));
#pragma unroll
    for (int off = 32; off; off >>= 1) mval = fmaxf(mval, __shfl_xor(mval, off));
    float p0 = __expf(sc0 - mval), p1 = __expf(sc1 - mval);
    float p2 = __expf(sc2 - mval), p3 = __expf(sc3 - mval);
    float S = p0 + p1 + p2 + p3;
#pragma unroll
    for (int off = 32; off; off >>= 1) S += __shfl_xor(S, off);
    float inv = 1.f / S;
    p0 *= inv; p1 *= inv; p2 *= inv; p3 *= inv;

    // ---- PV: claim_new[d] = sum_e p[e] * x[ev[e]][d], d = j*64+lane
    float cn[8];
#pragma unroll
    for (int j = 0; j < 8; j++) cn[j] = 0.f;
#pragma unroll
    for (int jj = 0; jj < 4; jj++) {
      float preg = (jj == 0) ? p0 : (jj == 1) ? p1 : (jj == 2) ? p2 : p3;
      int ebase = jj * 64;
      int ecnt = min(64, ne - ebase);
      if (ecnt > 0) {
        for (int el = 0; el < ecnt; el++) {
          float p = __shfl(preg, el);
          const float* er = x + (size_t)ev_id[ebase + el] * NHID;
#pragma unroll
          for (int j = 0; j < 8; j++) cn[j] += p * er[j * 64 + lane];
        }
      }
    }
    // ---- fused pooled sums (claim, claim_new, claim*claim_new)
    int cgid = cidx[c_list[coff + l]];
    const float* crow = x + (size_t)cgid * NHID;
#pragma unroll
    for (int j = 0; j < 8; j++) {
      float cl = crow[j * 64 + lane];
      s_cl[j] += cl;
      s_cn[j] += cn[j];
      s_pr[j] += cl * cn[j];
    }
  }
  float* gsg = gs + (size_t)g * 3 * NHID;
#pragma unroll
  for (int j = 0; j < 8; j++) {
    int d = j * 64 + lane;
    atomicAdd(&gsg[d], s_cl[j]);
    atomicAdd(&gsg[NHID + d], s_cn[j]);
    atomicAdd(&gsg[2 * NHID + d], s_pr[j]);
  }
}

// ---------------- k_out: res[g] = mean_concat[g] @ Wa + ba ----------------
__global__ __launch_bounds__(512) void k_out(
    const float* __restrict__ gs, const int* __restrict__ c_cnt,
    const float* __restrict__ Wa, const float* __restrict__ ba,
    float* __restrict__ out) {
  int g = blockIdx.x;
  int t = threadIdx.x; // 512
  __shared__ float mc[4 * NHID];
  const float* gsg = gs + (size_t)g * 3 * NHID;
  float inv = 1.f / (float)max(c_cnt[g], 1);
  float sc = gsg[t], sn = gsg[NHID + t], sp = gsg[2 * NHID + t];
  mc[t] = sc * inv;
  mc[NHID + t] = sn * inv;
  mc[2 * NHID + t] = (sc - sn) * inv;
  mc[3 * NHID + t] = sp * inv;
  __syncthreads();
  float acc = ba[t];
#pragma unroll 8
  for (int k = 0; k < 4 * NHID; k++) acc += mc[k] * Wa[(size_t)k * NHID + t];
  out[(size_t)g * NHID + t] = acc;
}

extern "C" void kernel_launch(void* const* d_in, const int* in_sizes, int n_in,
                              void* d_out, int out_size, void* d_ws, size_t ws_size,
                              hipStream_t stream) {
  const float* x = (const float*)d_in[0];
  const int* batch = (const int*)d_in[1];
  const int* cidx = (const int*)d_in[2];
  const int* eidx = (const int*)d_in[3];
  const float* Wc = (const float*)d_in[4];
  const float* bc = (const float*)d_in[5];
  const float* We = (const float*)d_in[6];
  const float* be = (const float*)d_in[7];
  const float* Wa = (const float*)d_in[8];
  const float* ba = (const float*)d_in[9];
  float* out = (float*)d_out;

  char* w = (char*)d_ws;
  int* cb = (int*)w;      w += NC * 4;
  int* eb = (int*)w;      w += NEV * 4;
  int* c_off = (int*)w;   w += NG * 4;
  int* c_cnt = (int*)w;   w += NG * 4;
  int* e_off = (int*)w;   w += NG * 4;
  int* e_cnt = (int*)w;   w += NG * 4;
  int* c_list = (int*)w;  w += NC * 4;
  int* e_list = (int*)w;  w += NEV * 4;
  float* wcp = (float*)w; w += (size_t)NC * PROJ * 4;
  float* wep = (float*)w; w += (size_t)NEV * PROJ * 4;
  float* gs = (float*)w;  w += (size_t)NG * 3 * NHID * 4;

  hipMemsetAsync(gs, 0, (size_t)NG * 3 * NHID * 4, stream);
  k_pre<<<(NC + NEV) / 256, 256, 0, stream>>>(batch, cidx, eidx, cb, eb);
  k_compact<<<NG, 256, 0, stream>>>(cb, eb, c_off, c_cnt, c_list, e_off, e_cnt, e_list);
  k_proj<<<(NC + NEV) / 8, 64, 0, stream>>>(x, cidx, eidx, Wc, bc, We, be, wcp, wep);
  k_attn<<<NG * CHUNKS_PER_G, 512, 0, stream>>>(x, cidx, eidx, wcp, wep, c_off, c_cnt,
                                                c_list, e_off, e_cnt, e_list, gs);
  k_out<<<NG, 512, 0, stream>>>(gs, c_cnt, Wa, ba, out);
}

// Round 2
// 138.599 us; speedup vs baseline: 3.2421x; 3.2421x over previous
//
#include <hip/hip_runtime.h>
#include <hip/hip_bf16.h>

#define NHID 512
#define PROJ 64
#define NC 4096
#define NEV 8192
#define NG 64
#define NCMAX 128
#define NE_CAP 256
#define DSLICES 4
#define DW 128

typedef __attribute__((ext_vector_type(8))) short s16x8;
typedef __attribute__((ext_vector_type(4))) float f32x4;

// ---- LDS layout (bytes) ----
#define P_S_STRIDE 264            // bf16 elems per row (256 + 8 pad), 528B, 16B-mult
#define P_S_BYTES  (NCMAX * P_S_STRIDE * 2)        // 67584
#define REGB_OFF   P_S_BYTES
#define WE_S_STRIDE 72            // bf16 elems (64 + 8 pad), 144B
#define WC_S_OFF   (REGB_OFF + NE_CAP * WE_S_STRIDE * 2)   // + 36864
#define CN_S_STRIDE 132           // f32 elems per row
#define MISC_OFF   (REGB_OFF + P_S_BYTES)          // 135168
#define SMEM_BYTES (MISC_OFF + 1024 + 512)         // 136704

static __device__ __forceinline__ unsigned short f2b(float f) {
  union { __hip_bfloat16 h; unsigned short u; } v;
  v.h = __float2bfloat16(f);
  return v.u;
}

// ---------------- k_pre: gather graph ids ----------------
__global__ void k_pre(const int* __restrict__ batch, const int* __restrict__ cidx,
                      const int* __restrict__ eidx, int* __restrict__ cb,
                      int* __restrict__ eb) {
  int i = blockIdx.x * 256 + threadIdx.x;
  if (i < NC) cb[i] = batch[cidx[i]];
  int j = i - NC;
  if (j >= 0 && j < NEV) eb[j] = batch[eidx[j]];
}

// ---------------- k_compact: stable per-graph compaction ----------------
__device__ void compact_one(const int* __restrict__ arr, int n, int g,
                            int* __restrict__ off_out, int* __restrict__ cnt_out,
                            int* __restrict__ list) {
  int t = threadIdx.x;
  int lane = t & 63, w = t >> 6;
  __shared__ int wsum[4];
  __shared__ int sless[4];
  int less = 0;
  for (int i = t; i < n; i += 256) less += (arr[i] < g) ? 1 : 0;
#pragma unroll
  for (int off = 32; off; off >>= 1) less += __shfl_xor(less, off);
  if (lane == 0) sless[w] = less;
  __syncthreads();
  int base = sless[0] + sless[1] + sless[2] + sless[3];
  if (t == 0) off_out[g] = base;
  int wbase = base;
  for (int chunk = 0; chunk < n; chunk += 256) {
    int i = chunk + t;
    bool f = (i < n) && (arr[i] == g);
    unsigned long long m = __ballot(f);
    if (lane == 0) wsum[w] = __popcll(m);
    __syncthreads();
    int prefix = 0;
    for (int k = 0; k < w; k++) prefix += wsum[k];
    int total = wsum[0] + wsum[1] + wsum[2] + wsum[3];
    if (f) list[wbase + prefix + __popcll(m & ((1ull << (unsigned)lane) - 1ull))] = i;
    wbase += total;
    __syncthreads();
  }
  if (t == 0) cnt_out[g] = wbase - base;
  __syncthreads();
}

__global__ __launch_bounds__(256) void k_compact(
    const int* __restrict__ cb, const int* __restrict__ eb,
    int* __restrict__ c_off, int* __restrict__ c_cnt, int* __restrict__ c_list,
    int* __restrict__ e_off, int* __restrict__ e_cnt, int* __restrict__ e_list) {
  int g = blockIdx.x;
  compact_one(cb, NC, g, c_off, c_cnt, c_list);
  compact_one(eb, NEV, g, e_off, e_cnt, e_list);
}

// ---------------- k_proj: weight_c / weight_e projections ----------------
__global__ __launch_bounds__(64) void k_proj(
    const float* __restrict__ x, const int* __restrict__ cidx,
    const int* __restrict__ eidx, const float* __restrict__ Wc,
    const float* __restrict__ bc, const float* __restrict__ We,
    const float* __restrict__ be, float* __restrict__ wcp, float* __restrict__ wep) {
  __shared__ float rows[8][NHID];
  int t = threadIdx.x;
  const float* W; const float* b; const int* idx; float* out; int base;
  if (blockIdx.x < NC / 8) {
    W = Wc; b = bc; idx = cidx; out = wcp; base = blockIdx.x * 8;
  } else {
    W = We; b = be; idx = eidx; out = wep; base = (blockIdx.x - NC / 8) * 8;
  }
  for (int r = 0; r < 8; r++) {
    const float4* src = (const float4*)(x + (size_t)idx[base + r] * NHID);
    float4* dst = (float4*)rows[r];
    dst[t] = src[t];
    dst[t + 64] = src[t + 64];
  }
  __syncthreads();
  float acc[8];
#pragma unroll
  for (int r = 0; r < 8; r++) acc[r] = b[t];
#pragma unroll 4
  for (int k = 0; k < NHID; k++) {
    float wv = W[k * PROJ + t];
#pragma unroll
    for (int r = 0; r < 8; r++) acc[r] += rows[r][k] * wv;
  }
  for (int r = 0; r < 8; r++) out[(size_t)(base + r) * PROJ + t] = acc[r];
}

// ---------------- k_attn: MFMA block-diagonal attention, one block per (g, d-slice) ----------------
__global__ __launch_bounds__(512) void k_attn(
    const float* __restrict__ x, const int* __restrict__ cidx,
    const int* __restrict__ eidx, const float* __restrict__ wcp,
    const float* __restrict__ wep, const int* __restrict__ c_off,
    const int* __restrict__ c_cnt, const int* __restrict__ c_list,
    const int* __restrict__ e_off, const int* __restrict__ e_cnt,
    const int* __restrict__ e_list, float* __restrict__ gs) {
  __shared__ __align__(16) char smem[SMEM_BYTES];
  unsigned short* P_s  = (unsigned short*)(smem);
  unsigned short* we_s = (unsigned short*)(smem + REGB_OFF);
  unsigned short* wc_s = (unsigned short*)(smem + WC_S_OFF);
  unsigned short* evT  = (unsigned short*)(smem + REGB_OFF);
  unsigned int*   evT32 = (unsigned int*)(smem + REGB_OFF);
  float*          cn_s = (float*)(smem + REGB_OFF);
  int* ev_id = (int*)(smem + MISC_OFF);
  int* cl_id = (int*)(smem + MISC_OFF + 1024);

  int g = blockIdx.x >> 2;
  int ds = blockIdx.x & 3;
  int dsbase = ds * DW;
  int t = threadIdx.x, lane = t & 63, w = t >> 6;
  int ln = lane & 15, kb = lane >> 4;

  int ne = min(e_cnt[g], NE_CAP);
  int eoff = e_off[g];
  int nloc = min(c_cnt[g], NCMAX);
  int coff = c_off[g];
  if (nloc <= 0) return;
  int KT = (ne + 31) >> 5;   // K-steps of 32 over evidence
  int NT = KT * 2;           // 16-wide n-tiles to cover ceil32(ne)

  // ---- phase 0: stage ids + we_s + wc_s (bf16) ----
  for (int e = t; e < NE_CAP; e += 512)
    ev_id[e] = (e < ne) ? (int)eidx[e_list[eoff + e]] : 0;
  if (t < NCMAX) cl_id[t] = (t < nloc) ? (int)cidx[c_list[coff + t]] : 0;
  {
    int q = t & 15, er = t >> 4;  // 32 rows per pass, 16B per thread
    for (int base = 0; base < NE_CAP; base += 32) {
      int e = base + er;
      float4 v = make_float4(0.f, 0.f, 0.f, 0.f);
      if (e < ne) v = ((const float4*)(wep + (size_t)e_list[eoff + e] * PROJ))[q];
      unsigned short* dst = we_s + e * WE_S_STRIDE + q * 4;
      dst[0] = f2b(v.x); dst[1] = f2b(v.y); dst[2] = f2b(v.z); dst[3] = f2b(v.w);
    }
    for (int base = 0; base < NCMAX; base += 32) {
      int c = base + er;
      float4 v = make_float4(0.f, 0.f, 0.f, 0.f);
      if (c < nloc) v = ((const float4*)(wcp + (size_t)c_list[coff + c] * PROJ))[q];
      unsigned short* dst = wc_s + c * WE_S_STRIDE + q * 4;
      dst[0] = f2b(v.x); dst[1] = f2b(v.y); dst[2] = f2b(v.z); dst[3] = f2b(v.w);
    }
  }
  __syncthreads();

  // ---- score phase: S = wc @ we^T via MFMA; wave w owns claims [16w,16w+16), all n ----
  {
    f32x4 sa[16];
#pragma unroll
    for (int i = 0; i < 16; i++) sa[i] = (f32x4){0.f, 0.f, 0.f, 0.f};
    const unsigned short* arow = wc_s + ((w << 4) + ln) * WE_S_STRIDE;
#pragma unroll
    for (int ks = 0; ks < 2; ks++) {
      s16x8 af = *(const s16x8*)(arow + ks * 32 + kb * 8);
#pragma unroll
      for (int nt = 0; nt < 16; nt++) {
        if (nt < NT) {
          s16x8 bf = *(const s16x8*)(we_s + (nt * 16 + ln) * WE_S_STRIDE + ks * 32 + kb * 8);
          sa[nt] = __builtin_amdgcn_mfma_f32_16x16x32_bf16(af, bf, sa[nt], 0, 0, 0);
        }
      }
    }
    // softmax per claim row (row = (lane>>4)*4 + r, col = nt*16 + (lane&15))
#pragma unroll
    for (int r = 0; r < 4; r++) {
      int claim = (w << 4) + (kb << 2) + r;
      float mx = -1e30f;
#pragma unroll
      for (int nt = 0; nt < 16; nt++) {
        if (nt < NT) {
          float v = sa[nt][r];
          v = (nt * 16 + ln < ne) ? v : -1e30f;
          sa[nt][r] = v;
          mx = fmaxf(mx, v);
        }
      }
      mx = fmaxf(mx, __shfl_xor(mx, 1));
      mx = fmaxf(mx, __shfl_xor(mx, 2));
      mx = fmaxf(mx, __shfl_xor(mx, 4));
      mx = fmaxf(mx, __shfl_xor(mx, 8));
      float sum = 0.f;
#pragma unroll
      for (int nt = 0; nt < 16; nt++) {
        if (nt < NT) {
          float p = __expf(sa[nt][r] - mx);
          sa[nt][r] = p;
          sum += p;
        }
      }
      sum += __shfl_xor(sum, 1);
      sum += __shfl_xor(sum, 2);
      sum += __shfl_xor(sum, 4);
      sum += __shfl_xor(sum, 8);
      float inv = 1.f / sum;
#pragma unroll
      for (int nt = 0; nt < 16; nt++) {
        if (nt < NT)
          P_s[claim * P_S_STRIDE + nt * 16 + ln] = f2b(sa[nt][r] * inv);
      }
    }
  }
  __syncthreads();   // P_s done; we_s/wc_s region free

  // ---- stage evT[d][e] bf16 (transposed evidence slice) ----
  for (int idx = t; idx < DW * (NE_CAP / 2); idx += 512) {
    int d = idx & (DW - 1);
    int ep = idx >> 7;
    int e0 = ep * 2;
    float f0 = 0.f, f1 = 0.f;
    if (e0 < ne)     f0 = x[(size_t)ev_id[e0] * NHID + dsbase + d];
    if (e0 + 1 < ne) f1 = x[(size_t)ev_id[e0 + 1] * NHID + dsbase + d];
    evT32[d * (P_S_STRIDE / 2) + ep] = (unsigned)f2b(f0) | ((unsigned)f2b(f1) << 16);
  }
  __syncthreads();

  // ---- PV phase: cn = P @ ev via MFMA; wave tile 32m x 64n ----
  int mw = w >> 1, nw = w & 1;
  int m0 = mw * 32, n0 = nw * 64;
  f32x4 pc[8];
#pragma unroll
  for (int i = 0; i < 8; i++) pc[i] = (f32x4){0.f, 0.f, 0.f, 0.f};
  {
    const unsigned short* prow0 = P_s + (m0 + ln) * P_S_STRIDE + kb * 8;
    const unsigned short* prow1 = prow0 + 16 * P_S_STRIDE;
#pragma unroll
    for (int kt = 0; kt < 8; kt++) {
      if (kt < KT) {
        int k0 = kt * 32;
        s16x8 a0 = *(const s16x8*)(prow0 + k0);
        s16x8 a1 = *(const s16x8*)(prow1 + k0);
#pragma unroll
        for (int nt = 0; nt < 4; nt++) {
          s16x8 bf = *(const s16x8*)(evT + (n0 + nt * 16 + ln) * P_S_STRIDE + k0 + kb * 8);
          pc[nt]     = __builtin_amdgcn_mfma_f32_16x16x32_bf16(a0, bf, pc[nt], 0, 0, 0);
          pc[4 + nt] = __builtin_amdgcn_mfma_f32_16x16x32_bf16(a1, bf, pc[4 + nt], 0, 0, 0);
        }
      }
    }
  }
  __syncthreads();   // all waves done reading evT

  // ---- dump cn to LDS (reuse evT region) ----
#pragma unroll
  for (int mi = 0; mi < 2; mi++) {
#pragma unroll
    for (int nt = 0; nt < 4; nt++) {
      f32x4 v = pc[mi * 4 + nt];
#pragma unroll
      for (int r = 0; r < 4; r++)
        cn_s[(m0 + mi * 16 + (kb << 2) + r) * CN_S_STRIDE + n0 + nt * 16 + ln] = v[r];
    }
  }
  __syncthreads();

  // ---- pooled sums: claim, claim_new, claim*claim_new over this d-slice ----
  {
    int d = t & (DW - 1);
    int mg = t >> 7;   // 4 claim-groups
    float scl = 0.f, scn = 0.f, spr = 0.f;
    for (int m = mg; m < nloc; m += 4) {
      float cl = x[(size_t)cl_id[m] * NHID + dsbase + d];
      float cn = cn_s[m * CN_S_STRIDE + d];
      scl += cl; scn += cn; spr += cl * cn;
    }
    float* gsg = gs + (size_t)g * 3 * NHID + dsbase + d;
    atomicAdd(gsg, scl);
    atomicAdd(gsg + NHID, scn);
    atomicAdd(gsg + 2 * NHID, spr);
  }
}

// ---------------- k_out: res[g] = mean_concat[g] @ Wa + ba (n-sliced, k-strips) ----------------
__global__ __launch_bounds__(512) void k_out(
    const float* __restrict__ gs, const int* __restrict__ c_cnt,
    const float* __restrict__ Wa, const float* __restrict__ ba,
    float* __restrict__ out) {
  int g = blockIdx.x >> 2, ns = blockIdx.x & 3;
  int t = threadIdx.x;
  int kq = t >> 7, nl = t & 127;
  int n = ns * 128 + nl;
  __shared__ float mc[4 * NHID];
  __shared__ float red[4][128];
  const float* gsg = gs + (size_t)g * 3 * NHID;
  float inv = 1.f / (float)max(c_cnt[g], 1);
  {
    int i = t;  // 512 threads cover NHID==512
    float sc = gsg[i], sn = gsg[NHID + i], sp = gsg[2 * NHID + i];
    mc[i] = sc * inv;
    mc[NHID + i] = sn * inv;
    mc[2 * NHID + i] = (sc - sn) * inv;
    mc[3 * NHID + i] = sp * inv;
  }
  __syncthreads();
  float acc = 0.f;
  const float* wcol = Wa + n;
#pragma unroll 8
  for (int k = kq * 512; k < kq * 512 + 512; k++) acc += mc[k] * wcol[(size_t)k * NHID];
  red[kq][nl] = acc;
  __syncthreads();
  if (kq == 0)
    out[(size_t)g * NHID + n] = ba[n] + red[0][nl] + red[1][nl] + red[2][nl] + red[3][nl];
}

extern "C" void kernel_launch(void* const* d_in, const int* in_sizes, int n_in,
                              void* d_out, int out_size, void* d_ws, size_t ws_size,
                              hipStream_t stream) {
  const float* x = (const float*)d_in[0];
  const int* batch = (const int*)d_in[1];
  const int* cidx = (const int*)d_in[2];
  const int* eidx = (const int*)d_in[3];
  const float* Wc = (const float*)d_in[4];
  const float* bc = (const float*)d_in[5];
  const float* We = (const float*)d_in[6];
  const float* be = (const float*)d_in[7];
  const float* Wa = (const float*)d_in[8];
  const float* ba = (const float*)d_in[9];
  float* out = (float*)d_out;

  char* w = (char*)d_ws;
  int* cb = (int*)w;      w += NC * 4;
  int* eb = (int*)w;      w += NEV * 4;
  int* c_off = (int*)w;   w += NG * 4;
  int* c_cnt = (int*)w;   w += NG * 4;
  int* e_off = (int*)w;   w += NG * 4;
  int* e_cnt = (int*)w;   w += NG * 4;
  int* c_list = (int*)w;  w += NC * 4;
  int* e_list = (int*)w;  w += NEV * 4;
  float* wcp = (float*)w; w += (size_t)NC * PROJ * 4;
  float* wep = (float*)w; w += (size_t)NEV * PROJ * 4;
  float* gs = (float*)w;  w += (size_t)NG * 3 * NHID * 4;

  hipMemsetAsync(gs, 0, (size_t)NG * 3 * NHID * 4, stream);
  k_pre<<<(NC + NEV) / 256, 256, 0, stream>>>(batch, cidx, eidx, cb, eb);
  k_compact<<<NG, 256, 0, stream>>>(cb, eb, c_off, c_cnt, c_list, e_off, e_cnt, e_list);
  k_proj<<<(NC + NEV) / 8, 64, 0, stream>>>(x, cidx, eidx, Wc, bc, We, be, wcp, wep);
  k_attn<<<NG * DSLICES, 512, 0, stream>>>(x, cidx, eidx, wcp, wep, c_off, c_cnt,
                                           c_list, e_off, e_cnt, e_list, gs);
  k_out<<<NG * 4, 512, 0, stream>>>(gs, c_cnt, Wa, ba, out);
}

// Round 3
// 103.913 us; speedup vs baseline: 4.3243x; 1.3338x over previous
//
#include <hip/hip_runtime.h>
#include <hip/hip_bf16.h>

#define NHID 512
#define PROJ 64
#define NC 4096
#define NEV 8192
#define NG 64
#define NCMAX 128
#define NE_CAP 256
#define DSLICES 4
#define DW 128

typedef __attribute__((ext_vector_type(8))) short s16x8;
typedef __attribute__((ext_vector_type(8))) unsigned short u16x8;
typedef __attribute__((ext_vector_type(4))) float f32x4;

// ---- k_attn LDS layout (bytes) ----
#define P_S_STRIDE 264            // bf16 elems per row (256 + 8 pad), 528B
#define P_S_BYTES  (NCMAX * P_S_STRIDE * 2)        // 67584
#define REGB_OFF   P_S_BYTES
#define WE_S_STRIDE 72            // bf16 elems (64 + 8 pad), 144B
#define WC_S_OFF   (REGB_OFF + NE_CAP * WE_S_STRIDE * 2)
#define CN_S_STRIDE 132           // f32 elems per row
#define MISC_OFF   (REGB_OFF + P_S_BYTES)
#define SMEM_BYTES (MISC_OFF + 1024 + 512)

static __device__ __forceinline__ unsigned short f2b(float f) {
  union { __hip_bfloat16 h; unsigned short u; } v;
  v.h = __float2bfloat16(f);
  return v.u;
}

// ---------------- k_pre: gather graph ids ----------------
__global__ void k_pre(const int* __restrict__ batch, const int* __restrict__ cidx,
                      const int* __restrict__ eidx, int* __restrict__ cb,
                      int* __restrict__ eb) {
  int i = blockIdx.x * 256 + threadIdx.x;
  if (i < NC) cb[i] = batch[cidx[i]];
  int j = i - NC;
  if (j >= 0 && j < NEV) eb[j] = batch[eidx[j]];
}

// ---------------- k_compact: stable per-graph compaction ----------------
__device__ void compact_one(const int* __restrict__ arr, int n, int g,
                            int* __restrict__ off_out, int* __restrict__ cnt_out,
                            int* __restrict__ list) {
  int t = threadIdx.x;
  int lane = t & 63, w = t >> 6;
  __shared__ int wsum[4];
  __shared__ int sless[4];
  int less = 0;
  for (int i = t; i < n; i += 256) less += (arr[i] < g) ? 1 : 0;
#pragma unroll
  for (int off = 32; off; off >>= 1) less += __shfl_xor(less, off);
  if (lane == 0) sless[w] = less;
  __syncthreads();
  int base = sless[0] + sless[1] + sless[2] + sless[3];
  if (t == 0) off_out[g] = base;
  int wbase = base;
  for (int chunk = 0; chunk < n; chunk += 256) {
    int i = chunk + t;
    bool f = (i < n) && (arr[i] == g);
    unsigned long long m = __ballot(f);
    if (lane == 0) wsum[w] = __popcll(m);
    __syncthreads();
    int prefix = 0;
    for (int k = 0; k < w; k++) prefix += wsum[k];
    int total = wsum[0] + wsum[1] + wsum[2] + wsum[3];
    if (f) list[wbase + prefix + __popcll(m & ((1ull << (unsigned)lane) - 1ull))] = i;
    wbase += total;
    __syncthreads();
  }
  if (t == 0) cnt_out[g] = wbase - base;
  __syncthreads();
}

__global__ __launch_bounds__(256) void k_compact(
    const int* __restrict__ cb, const int* __restrict__ eb,
    int* __restrict__ c_off, int* __restrict__ c_cnt, int* __restrict__ c_list,
    int* __restrict__ e_off, int* __restrict__ e_cnt, int* __restrict__ e_list) {
  int g = blockIdx.x;
  compact_one(cb, NC, g, c_off, c_cnt, c_list);
  compact_one(eb, NEV, g, e_off, e_cnt, e_list);
}

// ---------------- k_t64: f32 [K][N] -> bf16 [N][K] tile transpose ----------------
__global__ __launch_bounds__(256) void k_t64(
    const float* __restrict__ Wc, const float* __restrict__ We,
    const float* __restrict__ Wa, unsigned short* __restrict__ WcT,
    unsigned short* __restrict__ WeT, unsigned short* __restrict__ WaT) {
  __shared__ float ts[64][65];
  int b = blockIdx.x;
  const float* src; unsigned short* dst; int K, N, kt, nt;
  if (b < 8)       { src = Wc; dst = WcT; K = 512;  N = 64;  kt = b;          nt = 0; }
  else if (b < 16) { src = We; dst = WeT; K = 512;  N = 64;  kt = b - 8;      nt = 0; }
  else             { src = Wa; dst = WaT; K = 2048; N = 512; kt = (b - 16) >> 3; nt = (b - 16) & 7; }
  int k0 = kt * 64, n0 = nt * 64;
  int t = threadIdx.x;
  int c = t & 63, r0 = t >> 6;
#pragma unroll
  for (int p = 0; p < 16; p++) {
    int r = r0 * 16 + p;
    ts[r][c] = src[(size_t)(k0 + r) * N + n0 + c];
  }
  __syncthreads();
  int n = t >> 2, q = t & 3;
  unsigned short tmp[16];
#pragma unroll
  for (int j = 0; j < 16; j++) tmp[j] = f2b(ts[q * 16 + j][n]);
  u16x8* dp = (u16x8*)(dst + (size_t)(n0 + n) * K + k0 + q * 16);
  dp[0] = *(u16x8*)tmp;
  dp[1] = *(u16x8*)(tmp + 8);
}

// ---------------- k_proj: MFMA GEMM, no LDS; out = bf16 ----------------
// C[12288x64] = bf16(x_gather[.x512]) @ bf16(W[512x64]) + b
__global__ __launch_bounds__(128) void k_proj(
    const float* __restrict__ x, const int* __restrict__ cidx,
    const int* __restrict__ eidx, const unsigned short* __restrict__ WcT,
    const unsigned short* __restrict__ WeT, const float* __restrict__ bc,
    const float* __restrict__ be, unsigned short* __restrict__ wcp,
    unsigned short* __restrict__ wep) {
  int b = blockIdx.x;
  const int* idx; const unsigned short* WT; const float* bias;
  unsigned short* out; int base;
  if (b < NC / 64) { idx = cidx; WT = WcT; bias = bc; out = wcp; base = b * 64; }
  else             { idx = eidx; WT = WeT; bias = be; out = wep; base = (b - NC / 64) * 64; }
  int t = threadIdx.x, lane = t & 63, w = t >> 6;
  int ln = lane & 15, kb = lane >> 4;
  int m0 = w * 32;
  const float* xr0 = x + (size_t)idx[base + m0 + ln] * NHID;
  const float* xr1 = x + (size_t)idx[base + m0 + 16 + ln] * NHID;
  float bv[4];
#pragma unroll
  for (int nt = 0; nt < 4; nt++) bv[nt] = bias[nt * 16 + ln];
  f32x4 acc[2][4];
#pragma unroll
  for (int mi = 0; mi < 2; mi++)
#pragma unroll
    for (int nt = 0; nt < 4; nt++) acc[mi][nt] = (f32x4){0.f, 0.f, 0.f, 0.f};

#pragma unroll
  for (int kt = 0; kt < 8; kt++) {
#pragma unroll
    for (int ks = 0; ks < 2; ks++) {
      int k0 = kt * 64 + ks * 32 + kb * 8;
      float4 p0 = *(const float4*)(xr0 + k0);
      float4 p1 = *(const float4*)(xr0 + k0 + 4);
      float4 q0 = *(const float4*)(xr1 + k0);
      float4 q1 = *(const float4*)(xr1 + k0 + 4);
      s16x8 a0, a1;
      a0[0] = (short)f2b(p0.x); a0[1] = (short)f2b(p0.y);
      a0[2] = (short)f2b(p0.z); a0[3] = (short)f2b(p0.w);
      a0[4] = (short)f2b(p1.x); a0[5] = (short)f2b(p1.y);
      a0[6] = (short)f2b(p1.z); a0[7] = (short)f2b(p1.w);
      a1[0] = (short)f2b(q0.x); a1[1] = (short)f2b(q0.y);
      a1[2] = (short)f2b(q0.z); a1[3] = (short)f2b(q0.w);
      a1[4] = (short)f2b(q1.x); a1[5] = (short)f2b(q1.y);
      a1[6] = (short)f2b(q1.z); a1[7] = (short)f2b(q1.w);
#pragma unroll
      for (int nt = 0; nt < 4; nt++) {
        s16x8 bf = *(const s16x8*)(WT + (size_t)(nt * 16 + ln) * NHID + k0);
        acc[0][nt] = __builtin_amdgcn_mfma_f32_16x16x32_bf16(a0, bf, acc[0][nt], 0, 0, 0);
        acc[1][nt] = __builtin_amdgcn_mfma_f32_16x16x32_bf16(a1, bf, acc[1][nt], 0, 0, 0);
      }
    }
  }
#pragma unroll
  for (int mi = 0; mi < 2; mi++)
#pragma unroll
    for (int nt = 0; nt < 4; nt++)
#pragma unroll
      for (int r = 0; r < 4; r++) {
        int rowg = base + m0 + mi * 16 + kb * 4 + r;
        out[(size_t)rowg * PROJ + nt * 16 + ln] = f2b(acc[mi][nt][r] + bv[nt]);
      }
}

// ---------------- k_attn: MFMA block-diagonal attention ----------------
__global__ __launch_bounds__(512) void k_attn(
    const float* __restrict__ x, const int* __restrict__ cidx,
    const int* __restrict__ eidx, const unsigned short* __restrict__ wcp,
    const unsigned short* __restrict__ wep, const int* __restrict__ c_off,
    const int* __restrict__ c_cnt, const int* __restrict__ c_list,
    const int* __restrict__ e_off, const int* __restrict__ e_cnt,
    const int* __restrict__ e_list, float* __restrict__ gs) {
  __shared__ __align__(16) char smem[SMEM_BYTES];
  unsigned short* P_s  = (unsigned short*)(smem);
  unsigned short* we_s = (unsigned short*)(smem + REGB_OFF);
  unsigned short* wc_s = (unsigned short*)(smem + WC_S_OFF);
  unsigned short* evT  = (unsigned short*)(smem + REGB_OFF);
  unsigned int*   evT32 = (unsigned int*)(smem + REGB_OFF);
  float*          cn_s = (float*)(smem + REGB_OFF);
  int* ev_id = (int*)(smem + MISC_OFF);
  int* cl_id = (int*)(smem + MISC_OFF + 1024);

  int g = blockIdx.x >> 2;
  int ds = blockIdx.x & 3;
  int dsbase = ds * DW;
  int t = threadIdx.x, lane = t & 63, w = t >> 6;
  int ln = lane & 15, kb = lane >> 4;

  int ne = min(e_cnt[g], NE_CAP);
  int eoff = e_off[g];
  int nloc = min(c_cnt[g], NCMAX);
  int coff = c_off[g];
  if (nloc <= 0) return;
  int KT = (ne + 31) >> 5;
  int NT = KT * 2;

  // ---- phase 0: stage ids + we_s + wc_s (raw bf16 copies) ----
  for (int e = t; e < NE_CAP; e += 512)
    ev_id[e] = (e < ne) ? (int)eidx[e_list[eoff + e]] : 0;
  if (t < NCMAX) cl_id[t] = (t < nloc) ? (int)cidx[c_list[coff + t]] : 0;
  {
    int q = t & 7, er = t >> 3;  // 64 rows per pass, 16B per thread
    for (int base_ = 0; base_ < NE_CAP; base_ += 64) {
      int e = base_ + er;
      u16x8 v = (u16x8){0, 0, 0, 0, 0, 0, 0, 0};
      if (e < ne) v = *(const u16x8*)(wep + (size_t)e_list[eoff + e] * PROJ + q * 8);
      *(u16x8*)(we_s + e * WE_S_STRIDE + q * 8) = v;
    }
    for (int base_ = 0; base_ < NCMAX; base_ += 64) {
      int c = base_ + er;
      u16x8 v = (u16x8){0, 0, 0, 0, 0, 0, 0, 0};
      if (c < nloc) v = *(const u16x8*)(wcp + (size_t)c_list[coff + c] * PROJ + q * 8);
      *(u16x8*)(wc_s + c * WE_S_STRIDE + q * 8) = v;
    }
  }
  __syncthreads();

  // ---- score phase: S = wc @ we^T via MFMA ----
  {
    f32x4 sa[16];
#pragma unroll
    for (int i = 0; i < 16; i++) sa[i] = (f32x4){0.f, 0.f, 0.f, 0.f};
    const unsigned short* arow = wc_s + ((w << 4) + ln) * WE_S_STRIDE;
#pragma unroll
    for (int ks = 0; ks < 2; ks++) {
      s16x8 af = *(const s16x8*)(arow + ks * 32 + kb * 8);
#pragma unroll
      for (int nt = 0; nt < 16; nt++) {
        if (nt < NT) {
          s16x8 bf = *(const s16x8*)(we_s + (nt * 16 + ln) * WE_S_STRIDE + ks * 32 + kb * 8);
          sa[nt] = __builtin_amdgcn_mfma_f32_16x16x32_bf16(af, bf, sa[nt], 0, 0, 0);
        }
      }
    }
#pragma unroll
    for (int r = 0; r < 4; r++) {
      int claim = (w << 4) + (kb << 2) + r;
      float mx = -1e30f;
#pragma unroll
      for (int nt = 0; nt < 16; nt++) {
        if (nt < NT) {
          float v = sa[nt][r];
          v = (nt * 16 + ln < ne) ? v : -1e30f;
          sa[nt][r] = v;
          mx = fmaxf(mx, v);
        }
      }
      mx = fmaxf(mx, __shfl_xor(mx, 1));
      mx = fmaxf(mx, __shfl_xor(mx, 2));
      mx = fmaxf(mx, __shfl_xor(mx, 4));
      mx = fmaxf(mx, __shfl_xor(mx, 8));
      float sum = 0.f;
#pragma unroll
      for (int nt = 0; nt < 16; nt++) {
        if (nt < NT) {
          float p = __expf(sa[nt][r] - mx);
          sa[nt][r] = p;
          sum += p;
        }
      }
      sum += __shfl_xor(sum, 1);
      sum += __shfl_xor(sum, 2);
      sum += __shfl_xor(sum, 4);
      sum += __shfl_xor(sum, 8);
      float inv = 1.f / sum;
#pragma unroll
      for (int nt = 0; nt < 16; nt++) {
        if (nt < NT)
          P_s[claim * P_S_STRIDE + nt * 16 + ln] = f2b(sa[nt][r] * inv);
      }
    }
  }
  __syncthreads();

  // ---- stage evT[d][e] bf16 ----
  for (int idx = t; idx < DW * (NE_CAP / 2); idx += 512) {
    int d = idx & (DW - 1);
    int ep = idx >> 7;
    int e0 = ep * 2;
    float f0 = 0.f, f1 = 0.f;
    if (e0 < ne)     f0 = x[(size_t)ev_id[e0] * NHID + dsbase + d];
    if (e0 + 1 < ne) f1 = x[(size_t)ev_id[e0 + 1] * NHID + dsbase + d];
    evT32[d * (P_S_STRIDE / 2) + ep] = (unsigned)f2b(f0) | ((unsigned)f2b(f1) << 16);
  }
  __syncthreads();

  // ---- PV phase ----
  int mw = w >> 1, nw = w & 1;
  int m0 = mw * 32, n0 = nw * 64;
  f32x4 pc[8];
#pragma unroll
  for (int i = 0; i < 8; i++) pc[i] = (f32x4){0.f, 0.f, 0.f, 0.f};
  {
    const unsigned short* prow0 = P_s + (m0 + ln) * P_S_STRIDE + kb * 8;
    const unsigned short* prow1 = prow0 + 16 * P_S_STRIDE;
#pragma unroll
    for (int kt = 0; kt < 8; kt++) {
      if (kt < KT) {
        int k0 = kt * 32;
        s16x8 a0 = *(const s16x8*)(prow0 + k0);
        s16x8 a1 = *(const s16x8*)(prow1 + k0);
#pragma unroll
        for (int nt = 0; nt < 4; nt++) {
          s16x8 bf = *(const s16x8*)(evT + (n0 + nt * 16 + ln) * P_S_STRIDE + k0 + kb * 8);
          pc[nt]     = __builtin_amdgcn_mfma_f32_16x16x32_bf16(a0, bf, pc[nt], 0, 0, 0);
          pc[4 + nt] = __builtin_amdgcn_mfma_f32_16x16x32_bf16(a1, bf, pc[4 + nt], 0, 0, 0);
        }
      }
    }
  }
  __syncthreads();

  // ---- dump cn to LDS ----
#pragma unroll
  for (int mi = 0; mi < 2; mi++) {
#pragma unroll
    for (int nt = 0; nt < 4; nt++) {
      f32x4 v = pc[mi * 4 + nt];
#pragma unroll
      for (int r = 0; r < 4; r++)
        cn_s[(m0 + mi * 16 + (kb << 2) + r) * CN_S_STRIDE + n0 + nt * 16 + ln] = v[r];
    }
  }
  __syncthreads();

  // ---- pooled sums ----
  {
    int d = t & (DW - 1);
    int mg = t >> 7;
    float scl = 0.f, scn = 0.f, spr = 0.f;
    for (int m = mg; m < nloc; m += 4) {
      float cl = x[(size_t)cl_id[m] * NHID + dsbase + d];
      float cn = cn_s[m * CN_S_STRIDE + d];
      scl += cl; scn += cn; spr += cl * cn;
    }
    float* gsg = gs + (size_t)g * 3 * NHID + dsbase + d;
    atomicAdd(gsg, scl);
    atomicAdd(gsg + NHID, scn);
    atomicAdd(gsg + 2 * NHID, spr);
  }
}

// ---------------- k_mean: mc_bf[g][2048] = mean-concat (bf16) ----------------
__global__ __launch_bounds__(512) void k_mean(const float* __restrict__ gs,
                                              const int* __restrict__ c_cnt,
                                              unsigned short* __restrict__ mc) {
  int g = blockIdx.x, t = threadIdx.x;
  const float* gsg = gs + (size_t)g * 3 * NHID;
  float inv = 1.f / (float)max(c_cnt[g], 1);
  float sc = gsg[t], sn = gsg[NHID + t], sp = gsg[2 * NHID + t];
  unsigned short* m = mc + (size_t)g * 4 * NHID;
  m[t] = f2b(sc * inv);
  m[NHID + t] = f2b(sn * inv);
  m[2 * NHID + t] = f2b((sc - sn) * inv);
  m[3 * NHID + t] = f2b(sp * inv);
}

// ---------------- k_out: out = mc @ Wa + ba via MFMA (K-split, atomic) ----------------
__global__ __launch_bounds__(256) void k_out(
    const unsigned short* __restrict__ mc, const unsigned short* __restrict__ WaT,
    const float* __restrict__ ba, float* __restrict__ out) {
  int ns = blockIdx.x & 7, kstrip = blockIdx.x >> 3;
  int n0 = ns * 64, kbase = kstrip * 512;
  int t = threadIdx.x, lane = t & 63, w = t >> 6;
  int ln = lane & 15, kb = lane >> 4;
  f32x4 acc[4];
#pragma unroll
  for (int nt = 0; nt < 4; nt++) acc[nt] = (f32x4){0.f, 0.f, 0.f, 0.f};
  const unsigned short* arow = mc + (size_t)(w * 16 + ln) * (4 * NHID);
#pragma unroll
  for (int kt = 0; kt < 16; kt++) {
    int k0 = kbase + kt * 32 + kb * 8;
    s16x8 af = *(const s16x8*)(arow + k0);
#pragma unroll
    for (int nt = 0; nt < 4; nt++) {
      s16x8 bf = *(const s16x8*)(WaT + (size_t)(n0 + nt * 16 + ln) * (4 * NHID) + k0);
      acc[nt] = __builtin_amdgcn_mfma_f32_16x16x32_bf16(af, bf, acc[nt], 0, 0, 0);
    }
  }
#pragma unroll
  for (int nt = 0; nt < 4; nt++)
#pragma unroll
    for (int r = 0; r < 4; r++) {
      int gg = w * 16 + kb * 4 + r;
      int col = n0 + nt * 16 + ln;
      float v = acc[nt][r];
      if (kstrip == 0) v += ba[col];
      atomicAdd(out + (size_t)gg * NHID + col, v);
    }
}

extern "C" void kernel_launch(void* const* d_in, const int* in_sizes, int n_in,
                              void* d_out, int out_size, void* d_ws, size_t ws_size,
                              hipStream_t stream) {
  const float* x = (const float*)d_in[0];
  const int* batch = (const int*)d_in[1];
  const int* cidx = (const int*)d_in[2];
  const int* eidx = (const int*)d_in[3];
  const float* Wc = (const float*)d_in[4];
  const float* bc = (const float*)d_in[5];
  const float* We = (const float*)d_in[6];
  const float* be = (const float*)d_in[7];
  const float* Wa = (const float*)d_in[8];
  const float* ba = (const float*)d_in[9];
  float* out = (float*)d_out;

  char* w = (char*)d_ws;
  int* cb = (int*)w;      w += NC * 4;
  int* eb = (int*)w;      w += NEV * 4;
  int* c_off = (int*)w;   w += NG * 4;
  int* c_cnt = (int*)w;   w += NG * 4;
  int* e_off = (int*)w;   w += NG * 4;
  int* e_cnt = (int*)w;   w += NG * 4;
  int* c_list = (int*)w;  w += NC * 4;
  int* e_list = (int*)w;  w += NEV * 4;
  unsigned short* wcp = (unsigned short*)w; w += (size_t)NC * PROJ * 2;
  unsigned short* wep = (unsigned short*)w; w += (size_t)NEV * PROJ * 2;
  unsigned short* WcT = (unsigned short*)w; w += (size_t)PROJ * NHID * 2;
  unsigned short* WeT = (unsigned short*)w; w += (size_t)PROJ * NHID * 2;
  unsigned short* WaT = (unsigned short*)w; w += (size_t)NHID * 4 * NHID * 2;
  unsigned short* mcb = (unsigned short*)w; w += (size_t)NG * 4 * NHID * 2;
  float* gs = (float*)w;  w += (size_t)NG * 3 * NHID * 4;

  hipMemsetAsync(gs, 0, (size_t)NG * 3 * NHID * 4, stream);
  hipMemsetAsync(out, 0, (size_t)NG * NHID * 4, stream);
  k_pre<<<(NC + NEV) / 256, 256, 0, stream>>>(batch, cidx, eidx, cb, eb);
  k_compact<<<NG, 256, 0, stream>>>(cb, eb, c_off, c_cnt, c_list, e_off, e_cnt, e_list);
  k_t64<<<16 + 256, 256, 0, stream>>>(Wc, We, Wa, WcT, WeT, WaT);
  k_proj<<<(NC + NEV) / 64, 128, 0, stream>>>(x, cidx, eidx, WcT, WeT, bc, be, wcp, wep);
  k_attn<<<NG * DSLICES, 512, 0, stream>>>(x, cidx, eidx, wcp, wep, c_off, c_cnt,
                                           c_list, e_off, e_cnt, e_list, gs);
  k_mean<<<NG, 512, 0, stream>>>(gs, c_cnt, mcb);
  k_out<<<32, 256, 0, stream>>>(mcb, WaT, ba, out);
}